// Round 3
// baseline (298.475 us; speedup 1.0000x reference)
//
#include <hip/hip_runtime.h>
#include <hip/hip_bf16.h>

typedef __bf16 bf16;
typedef __bf16 bf16x4 __attribute__((ext_vector_type(4)));
typedef __bf16 bf16x8 __attribute__((ext_vector_type(8)));
typedef float  f32x4  __attribute__((ext_vector_type(4)));

#define NEG_INF (-1e9f)
#define N_SCENES 2048

// ---------------------------------------------------------------------------
// Prep: block 0 computes exclusive prefix sum of agents_per_sample (B=2048);
// blocks 1..64 convert w_in / w_out fp32 -> bf16 into workspace.
// ---------------------------------------------------------------------------
__global__ __launch_bounds__(256) void prep_kernel(
    const float* __restrict__ w_in, const float* __restrict__ w_out,
    const int* __restrict__ agents,
    bf16* __restrict__ w_in_b, bf16* __restrict__ w_out_b, int* __restrict__ offs)
{
    __shared__ int tot[256];
    const int t = threadIdx.x;
    if (blockIdx.x == 0) {
        int loc[8]; int s = 0;
        #pragma unroll
        for (int j = 0; j < 8; ++j) { loc[j] = agents[t * 8 + j]; s += loc[j]; }
        tot[t] = s;
        __syncthreads();
        for (int o = 1; o < 256; o <<= 1) {
            int v = (t >= o) ? tot[t - o] : 0;
            __syncthreads();
            tot[t] += v;
            __syncthreads();
        }
        int run = tot[t] - s;
        #pragma unroll
        for (int j = 0; j < 8; ++j) { offs[t * 8 + j] = run; run += loc[j]; }
    } else {
        int i = (blockIdx.x - 1) * 1024 + t * 4;
        float4 v; bf16* dst;
        if (i < 49152) { v = *(const float4*)(w_in + i);            dst = w_in_b + i; }
        else           { v = *(const float4*)(w_out + (i - 49152)); dst = w_out_b + (i - 49152); }
        bf16x4 o = { (bf16)v.x, (bf16)v.y, (bf16)v.z, (bf16)v.w };
        *(bf16x4*)dst = o;
    }
}

// ---------------------------------------------------------------------------
// Fused attention: one block (4 waves) per scene; wave w owns head w.
// Restructured vs R2 to keep the live register set small (no 64-reg arrays):
//   stage1: runtime mt loop, xa[4] (16 regs) live per iteration
//   stage2: per-mt S->softmax->P->PV->ctx pipeline; kb/vb preloaded once
//   stage3: wo hoisted, ca read once per mt
// LDS 48KB (12KB/wave: qk[64][64] q|k cols, P overlays k, ctx overlays q;
// vT[32][64]); XOR swizzle c^=(row&7) on 16B chunks. One __syncthreads.
// MFMA 16x16x32_bf16: A[m=lane&15][k=quad*8+j], B(T row-major), C/D col=lane&15,
// row=quad*4+reg.
// ---------------------------------------------------------------------------
__global__ __launch_bounds__(256, 3) void attn_kernel(
    const float* __restrict__ att_in,
    const float* __restrict__ b_in, const float* __restrict__ b_out,
    const bf16* __restrict__ w_in_b, const bf16* __restrict__ w_out_b,
    const int* __restrict__ agents, const int* __restrict__ offs,
    float* __restrict__ out)
{
    __shared__ bf16 s_lds[4 * 6144];   // 48 KB

    const int b    = blockIdx.x;
    const int tid  = threadIdx.x;
    const int lane = tid & 63;
    const int w    = tid >> 6;         // wave id == head id
    const int h    = w;
    const int r    = lane & 15;
    const int qd   = lane >> 4;        // quad 0..3
    const int r7   = lane & 7;
    const int nb   = agents[b];
    const int off  = offs[b];
    const int mtc  = (nb + 15) >> 4;   // live m-tiles (1..4)
    const int mt16 = mtc << 4;

    bf16* qk = s_lds + w * 6144;       // [64][64]
    bf16* vT = qk + 4096;              // [32][64]

    // zero-store output rows [mt16, 64)
    {
        const float4 z4 = make_float4(0.f, 0.f, 0.f, 0.f);
        const int nz = (64 - mt16) * 32;
        for (int i = tid; i < nz; i += 256) {
            int row = mt16 + (i >> 5);
            *(float4*)(out + ((size_t)b * 64 + row) * 128 + (i & 31) * 4) = z4;
        }
    }

    // zero vT boundary key-tile [mt16, mt16+16) when mtc odd (PV K=32 pads)
    if (mtc & 1) {
        int zr = lane >> 1, half = lane & 1;
        int c = (2 * mtc + half) ^ (zr & 7);
        bf16x8 z8 = {(bf16)0.f,(bf16)0.f,(bf16)0.f,(bf16)0.f,
                     (bf16)0.f,(bf16)0.f,(bf16)0.f,(bf16)0.f};
        *(bf16x8*)(vT + zr * 64 + c * 8) = z8;
    }

    // ---- stage 1: q,k,v for this head; runtime mt loop keeps regs low ----
    for (int mt = 0; mt < mtc; ++mt) {
        const int xrow = mt * 16 + r;
        const bool vr = xrow < nb;
        const float* px = att_in + (((size_t)(off + xrow)) << 7) + qd * 8;
        bf16x8 xa[4];
        #pragma unroll
        for (int ks = 0; ks < 4; ++ks) {
            float4 lo = make_float4(0.f,0.f,0.f,0.f), hi = lo;
            if (vr) {
                lo = *(const float4*)(px + ks * 32);
                hi = *(const float4*)(px + ks * 32 + 4);
            }
            xa[ks] = (bf16x8){(bf16)lo.x,(bf16)lo.y,(bf16)lo.z,(bf16)lo.w,
                              (bf16)hi.x,(bf16)hi.y,(bf16)hi.z,(bf16)hi.w};
        }
        #pragma unroll
        for (int t = 0; t < 6; ++t) {
            const int kind = t >> 1, sub = t & 1;       // 0=q,1=k,2=v
            const int j0 = kind * 128 + h * 32 + sub * 16;
            const bf16* pw = w_in_b + (size_t)(j0 + r) * 128 + qd * 8;
            bf16x8 wb[4];
            #pragma unroll
            for (int ks = 0; ks < 4; ++ks)
                wb[ks] = *(const bf16x8*)(pw + ks * 32);
            const float bias = b_in[j0 + r];
            f32x4 acc = {0.f, 0.f, 0.f, 0.f};
            #pragma unroll
            for (int ks = 0; ks < 4; ++ks)
                acc = __builtin_amdgcn_mfma_f32_16x16x32_bf16(xa[ks], wb[ks], acc, 0, 0, 0);
            if (kind < 2) {
                const int chunk = kind * 4 + sub * 2 + (r >> 3);
                #pragma unroll
                for (int i = 0; i < 4; ++i) {
                    int row2 = mt * 16 + qd * 4 + i;
                    int c = chunk ^ (row2 & 7);
                    qk[row2 * 64 + c * 8 + r7] = (bf16)(acc[i] + bias);
                }
            } else {
                const int vrow = sub * 16 + r;           // dim within head
                const int c = (2 * mt + (qd >> 1)) ^ r7;
                bf16x4 pk = {(bf16)(acc[0]+bias), (bf16)(acc[1]+bias),
                             (bf16)(acc[2]+bias), (bf16)(acc[3]+bias)};
                *(bf16x4*)(vT + vrow * 64 + c * 8 + (qd & 1) * 4) = pk;
            }
        }
    }

    // ---- stage 2: per-mt S -> softmax -> P -> PV -> ctx ----
    bf16x8 kb[4];
    #pragma unroll
    for (int nt = 0; nt < 4; ++nt) {
        int row = nt * 16 + r;
        kb[nt] = *(const bf16x8*)(qk + row * 64 + ((4 + qd) ^ r7) * 8);
    }
    bf16x8 vb[2][2];
    #pragma unroll
    for (int hk = 0; hk < 2; ++hk)
        #pragma unroll
        for (int n2 = 0; n2 < 2; ++n2) {
            int row = n2 * 16 + r;
            vb[hk][n2] = *(const bf16x8*)(vT + row * 64 + ((hk * 4 + qd) ^ r7) * 8);
        }
    const int hkc = (mtc + 1) >> 1;
    const float scale = 0.17677669529663687f;           // 1/sqrt(32)
    bool kvalid[4];
    #pragma unroll
    for (int nt = 0; nt < 4; ++nt) kvalid[nt] = (nt < mtc) && ((nt * 16 + r) < nb);

    for (int mt = 0; mt < mtc; ++mt) {
        const int arow = mt * 16 + r;
        const bf16x8 qa = *(const bf16x8*)(qk + arow * 64 + (qd ^ r7) * 8);
        f32x4 S[4];
        #pragma unroll
        for (int nt = 0; nt < 4; ++nt)
            if (nt < mtc) {
                f32x4 z = {0.f, 0.f, 0.f, 0.f};
                S[nt] = __builtin_amdgcn_mfma_f32_16x16x32_bf16(qa, kb[nt], z, 0, 0, 0);
            }
        #pragma unroll
        for (int i = 0; i < 4; ++i) {
            float v[4]; float mx = NEG_INF;
            #pragma unroll
            for (int nt = 0; nt < 4; ++nt) {
                float val = kvalid[nt] ? S[nt][i] * scale : NEG_INF;
                v[nt] = val; mx = fmaxf(mx, val);
            }
            mx = fmaxf(mx, __shfl_xor(mx, 1));
            mx = fmaxf(mx, __shfl_xor(mx, 2));
            mx = fmaxf(mx, __shfl_xor(mx, 4));
            mx = fmaxf(mx, __shfl_xor(mx, 8));
            float l = 0.f;
            #pragma unroll
            for (int nt = 0; nt < 4; ++nt) { v[nt] = __expf(v[nt] - mx); l += v[nt]; }
            l += __shfl_xor(l, 1); l += __shfl_xor(l, 2);
            l += __shfl_xor(l, 4); l += __shfl_xor(l, 8);
            float rl = 1.0f / l;
            #pragma unroll
            for (int nt = 0; nt < 4; ++nt) S[nt][i] = v[nt] * rl;   // masked -> exact 0
        }
        // PV: P overlays k cols (kb already in regs); K=32 slabs
        f32x4 c0 = {0.f,0.f,0.f,0.f}, c1 = {0.f,0.f,0.f,0.f};
        for (int hk = 0; hk < hkc; ++hk) {
            #pragma unroll
            for (int n2 = 0; n2 < 2; ++n2) {
                const int chunk = 4 + n2 * 2 + (r >> 3);
                #pragma unroll
                for (int i = 0; i < 4; ++i) {
                    int row2 = mt * 16 + qd * 4 + i;
                    int c = chunk ^ (row2 & 7);
                    qk[row2 * 64 + c * 8 + r7] = (bf16)S[hk * 2 + n2][i];
                }
            }
            const bf16x8 pa = *(const bf16x8*)(qk + arow * 64 + ((4 + qd) ^ r7) * 8);
            c0 = __builtin_amdgcn_mfma_f32_16x16x32_bf16(pa, vb[hk][0], c0, 0, 0, 0);
            c1 = __builtin_amdgcn_mfma_f32_16x16x32_bf16(pa, vb[hk][1], c1, 0, 0, 0);
        }
        // ctx -> q cols (rows of this mt only; later mts read disjoint rows)
        #pragma unroll
        for (int n2 = 0; n2 < 2; ++n2) {
            const int chunk = n2 * 2 + (r >> 3);
            const f32x4 cc = n2 ? c1 : c0;
            #pragma unroll
            for (int i = 0; i < 4; ++i) {
                int row2 = mt * 16 + qd * 4 + i;
                int c = chunk ^ (row2 & 7);
                qk[row2 * 64 + c * 8 + r7] = (bf16)cc[i];
            }
        }
    }
    __syncthreads();

    // ---- stage 3: out = (ctx @ w_out^T + b_out) * row_mask ----
    bf16x8 wo[2][4]; float ob[2];
    #pragma unroll
    for (int t2 = 0; t2 < 2; ++t2) {
        const int j0 = (w * 2 + t2) * 16;
        const bf16* pw = w_out_b + (size_t)(j0 + r) * 128 + qd * 8;
        #pragma unroll
        for (int ks = 0; ks < 4; ++ks)
            wo[t2][ks] = *(const bf16x8*)(pw + ks * 32);
        ob[t2] = b_out[j0 + r];
    }
    for (int mt = 0; mt < mtc; ++mt) {
        const int arow = mt * 16 + r;
        bf16x8 ca[4];
        #pragma unroll
        for (int ks = 0; ks < 4; ++ks)
            ca[ks] = *(const bf16x8*)(s_lds + ks * 6144 + arow * 64 + (qd ^ r7) * 8);
        #pragma unroll
        for (int t2 = 0; t2 < 2; ++t2) {
            f32x4 acc = {0.f, 0.f, 0.f, 0.f};
            #pragma unroll
            for (int ks = 0; ks < 4; ++ks)
                acc = __builtin_amdgcn_mfma_f32_16x16x32_bf16(ca[ks], wo[t2][ks], acc, 0, 0, 0);
            const int j0 = (w * 2 + t2) * 16;
            #pragma unroll
            for (int i = 0; i < 4; ++i) {
                int row2 = mt * 16 + qd * 4 + i;
                float val = (row2 < nb) ? (acc[i] + ob[t2]) : 0.f;
                out[((size_t)b * 64 + row2) * 128 + j0 + r] = val;
            }
        }
    }
}

extern "C" void kernel_launch(void* const* d_in, const int* in_sizes, int n_in,
                              void* d_out, int out_size, void* d_ws, size_t ws_size,
                              hipStream_t stream)
{
    const float* att_in = (const float*)d_in[0];
    const float* w_in   = (const float*)d_in[1];
    const float* b_in   = (const float*)d_in[2];
    const float* w_out  = (const float*)d_in[3];
    const float* b_out  = (const float*)d_in[4];
    const int*   agents = (const int*)d_in[5];

    bf16* w_in_b  = (bf16*)d_ws;                         // 49152 * 2B
    bf16* w_out_b = w_in_b + 49152;                      // 16384 * 2B
    int*  offs    = (int*)((char*)d_ws + 98304 + 32768); // 2048 * 4B

    prep_kernel<<<65, 256, 0, stream>>>(w_in, w_out, agents, w_in_b, w_out_b, offs);
    attn_kernel<<<N_SCENES, 256, 0, stream>>>(att_in, b_in, b_out, w_in_b, w_out_b,
                                              agents, offs, (float*)d_out);
}

// Round 4
// 176.818 us; speedup vs baseline: 1.6880x; 1.6880x over previous
//
#include <hip/hip_runtime.h>
#include <hip/hip_bf16.h>

typedef __bf16 bf16;
typedef __bf16 bf16x4 __attribute__((ext_vector_type(4)));
typedef __bf16 bf16x8 __attribute__((ext_vector_type(8)));
typedef float  f32x4  __attribute__((ext_vector_type(4)));

#define NEG_INF (-1e9f)
#define N_SCENES 2048

// ---------------------------------------------------------------------------
// Prep: block 0: exclusive prefix sum of agents (B=2048); blocks 1..64:
// fp32 -> bf16 weight conversion into workspace.
// ---------------------------------------------------------------------------
__global__ __launch_bounds__(256) void prep_kernel(
    const float* __restrict__ w_in, const float* __restrict__ w_out,
    const int* __restrict__ agents,
    bf16* __restrict__ w_in_b, bf16* __restrict__ w_out_b, int* __restrict__ offs)
{
    __shared__ int tot[256];
    const int t = threadIdx.x;
    if (blockIdx.x == 0) {
        int loc[8]; int s = 0;
        #pragma unroll
        for (int j = 0; j < 8; ++j) { loc[j] = agents[t * 8 + j]; s += loc[j]; }
        tot[t] = s;
        __syncthreads();
        for (int o = 1; o < 256; o <<= 1) {
            int v = (t >= o) ? tot[t - o] : 0;
            __syncthreads();
            tot[t] += v;
            __syncthreads();
        }
        int run = tot[t] - s;
        #pragma unroll
        for (int j = 0; j < 8; ++j) { offs[t * 8 + j] = run; run += loc[j]; }
    } else {
        int i = (blockIdx.x - 1) * 1024 + t * 4;
        float4 v; bf16* dst;
        if (i < 49152) { v = *(const float4*)(w_in + i);            dst = w_in_b + i; }
        else           { v = *(const float4*)(w_out + (i - 49152)); dst = w_out_b + (i - 49152); }
        bf16x4 o = { (bf16)v.x, (bf16)v.y, (bf16)v.z, (bf16)v.w };
        *(bf16x4*)dst = o;
    }
}

// ---------------------------------------------------------------------------
// R4: operand-swapped fused attention. One block (4 waves) per scene; wave w
// owns head w. Stage1: Q^T,K^T = mfma(W, X^T), V = mfma(X, W) -> packed 8-B
// LDS writes as Q[agent][d], K[agent][d], vT[d][agent] (XOR-swizzled 16-B
// units). Stage2: S^T = K*Q^T (both frags contiguous b128 LDS reads);
// softmax reduces across quads (2 shfls); P^T and ctx^T via in-register
// quad-shuffles (ds_bpermute) - NO per-mt LDS round-trip. PV: O^T = V^T*P^T.
// Stage3: out^T = W_out*ctx^T -> float4 stores (lane holds 4 consecutive
// channels). LDS 48KB; 12KB/wave (Q 4K | K 4K | vT 4K); ctxS overlays Q.
// All loops compile-time unrolled with predicated bodies (R3 lesson).
// MFMA 16x16x32_bf16: A[m=lane&15][k=quad*8+jj], B[k=quad*8+jj][n=lane&15],
// C/D: col=lane&15, row=quad*4+reg.
// ---------------------------------------------------------------------------
__global__ __launch_bounds__(256, 3) void attn_kernel(
    const float* __restrict__ att_in,
    const float* __restrict__ b_in, const float* __restrict__ b_out,
    const bf16* __restrict__ w_in_b, const bf16* __restrict__ w_out_b,
    const int* __restrict__ agents, const int* __restrict__ offs,
    float* __restrict__ out)
{
    __shared__ bf16 s_lds[4 * 6144];   // 48 KB

    const int b    = blockIdx.x;
    const int tid  = threadIdx.x;
    const int lane = tid & 63;
    const int w    = tid >> 6;         // wave id == head id
    const int h    = w;
    const int r    = lane & 15;
    const int qd   = lane >> 4;        // quad 0..3
    const int q1   = qd & 1;
    const int qh   = qd >> 1;
    const int nb   = agents[b];
    const int off  = offs[b];
    const int mtc  = (nb + 15) >> 4;   // live m-tiles (1..4)

    bf16* Qld = s_lds + w * 6144;      // Q[64][32] swizzled; later ctxS[4 mt][64 lanes][8]
    bf16* Kld = Qld + 2048;            // K[64][32]
    bf16* vT  = Qld + 4096;            // vT[32][64]

    // ---- zero-fill output rows [nb, 64) ----
    {
        const float4 z4 = make_float4(0.f, 0.f, 0.f, 0.f);
        const int nz = (64 - nb) * 32;
        for (int i = tid; i < nz; i += 256) {
            int row = nb + (i >> 5);
            *(float4*)(out + ((size_t)b * 64 + row) * 128 + (i & 31) * 4) = z4;
        }
    }

    // ---- zero vT units for agents >= mtc*16 (keep PV inputs finite) ----
    {
        bf16x4 z4 = {(bf16)0.f,(bf16)0.f,(bf16)0.f,(bf16)0.f};
        int zrow = lane >> 1, zh = lane & 1;     // 32 rows x 2 halves
        #pragma unroll
        for (int u = 2; u < 8; ++u)
            if (u >= 2 * mtc) {
                int uu = u ^ (zrow & 7);
                *(bf16x4*)(vT + zrow * 64 + uu * 8 + zh * 4) = z4;
            }
    }

    // ---- x fragments from global (rows >= nb -> 0); serve as A and B ----
    bf16x8 xa[4][4];
    #pragma unroll
    for (int mt = 0; mt < 4; ++mt) {
        const int xrow = mt * 16 + r;
        const bool vr = xrow < nb;
        const float* px = att_in + (((size_t)(off + xrow)) << 7) + qd * 8;
        #pragma unroll
        for (int ks = 0; ks < 4; ++ks) {
            float4 lo = make_float4(0.f,0.f,0.f,0.f), hi = lo;
            if (vr) {
                lo = *(const float4*)(px + ks * 32);
                hi = *(const float4*)(px + ks * 32 + 4);
            }
            xa[mt][ks] = (bf16x8){(bf16)lo.x,(bf16)lo.y,(bf16)lo.z,(bf16)lo.w,
                                  (bf16)hi.x,(bf16)hi.y,(bf16)hi.z,(bf16)hi.w};
        }
    }

    // ---- stage 1: 6 output tiles (q jt0/1, k jt0/1, v jt0/1) ----
    #pragma unroll
    for (int t = 0; t < 6; ++t) {
        const int kind = t >> 1, jt = t & 1;     // 0=q,1=k,2=v
        const int j0 = kind * 128 + h * 32 + jt * 16;
        const bf16* pw = w_in_b + (size_t)(j0 + r) * 128 + qd * 8;
        bf16x8 wb[4];
        #pragma unroll
        for (int ks = 0; ks < 4; ++ks)
            wb[ks] = *(const bf16x8*)(pw + ks * 32);
        if (kind < 2) {
            // Q^T / K^T tile: D[j(16)][agent(16)]; store as Q[agent][d] packed
            const float4 b4 = *(const float4*)(b_in + j0 + qd * 4);
            bf16* dst = (kind == 0) ? Qld : Kld;
            #pragma unroll
            for (int mt = 0; mt < 4; ++mt)
                if (mt < mtc) {
                    f32x4 acc = {0.f,0.f,0.f,0.f};
                    #pragma unroll
                    for (int ks = 0; ks < 4; ++ks)
                        acc = __builtin_amdgcn_mfma_f32_16x16x32_bf16(wb[ks], xa[mt][ks], acc, 0, 0, 0);
                    bf16x4 pk = {(bf16)(acc[0]+b4.x), (bf16)(acc[1]+b4.y),
                                 (bf16)(acc[2]+b4.z), (bf16)(acc[3]+b4.w)};
                    int rowa = mt * 16 + r;                       // agent
                    int uu = (jt * 2 + qh) ^ (rowa & 3);          // 16-B unit swizzle
                    *(bf16x4*)(dst + rowa * 32 + uu * 8 + q1 * 4) = pk;
                }
        } else {
            // V tile: D[agent(16)][d(16)]; store as vT[d][agent] packed
            const float bv = b_in[j0 + r];
            #pragma unroll
            for (int mt = 0; mt < 4; ++mt)
                if (mt < mtc) {
                    f32x4 acc = {0.f,0.f,0.f,0.f};
                    #pragma unroll
                    for (int ks = 0; ks < 4; ++ks)
                        acc = __builtin_amdgcn_mfma_f32_16x16x32_bf16(xa[mt][ks], wb[ks], acc, 0, 0, 0);
                    bf16x4 pk = {(bf16)(acc[0]+bv), (bf16)(acc[1]+bv),
                                 (bf16)(acc[2]+bv), (bf16)(acc[3]+bv)};
                    int rowd = jt * 16 + r;                       // d within head
                    int uu = (mt * 2 + qh) ^ (rowd & 7);
                    *(bf16x4*)(vT + rowd * 64 + uu * 8 + q1 * 4) = pk;
                }
        }
    }

    // ---- stage 2 preloads: K A-frags, V^T A-frags, w_out A-frags ----
    bf16x8 kf[4];
    #pragma unroll
    for (int nt = 0; nt < 4; ++nt)
        if (nt < mtc) {
            int row = nt * 16 + r;
            kf[nt] = *(const bf16x8*)(Kld + row * 32 + (qd ^ (row & 3)) * 8);
        }
    bf16x8 vf[2][2];
    #pragma unroll
    for (int dt = 0; dt < 2; ++dt)
        #pragma unroll
        for (int hk = 0; hk < 2; ++hk) {
            int row = dt * 16 + r;
            vf[dt][hk] = *(const bf16x8*)(vT + row * 64 + ((hk * 4 + qd) ^ (row & 7)) * 8);
        }
    bf16x8 wof[2][4]; float4 bo4[2];
    #pragma unroll
    for (int t2 = 0; t2 < 2; ++t2) {
        const int jg = (w * 2 + t2) * 16;
        const bf16* pw = w_out_b + (size_t)(jg + r) * 128 + qd * 8;
        #pragma unroll
        for (int s = 0; s < 4; ++s)
            wof[t2][s] = *(const bf16x8*)(pw + s * 32);
        bo4[t2] = *(const float4*)(b_out + jg + qd * 4);
    }

    const float scale = 0.17677669529663687f;    // 1/sqrt(32)

    // ---- stage 2: per query-tile mt: S^T -> softmax -> P^T(shuffle) -> PV ----
    #pragma unroll
    for (int mt = 0; mt < 4; ++mt)
        if (mt < mtc) {
            int qrow = mt * 16 + r;
            bf16x8 qf = *(const bf16x8*)(Qld + qrow * 32 + (qd ^ (qrow & 3)) * 8);
            f32x4 S[4];
            #pragma unroll
            for (int nt = 0; nt < 4; ++nt)
                if (nt < mtc) {
                    f32x4 z = {0.f,0.f,0.f,0.f};
                    S[nt] = __builtin_amdgcn_mfma_f32_16x16x32_bf16(kf[nt], qf, z, 0, 0, 0);
                }
            // masked softmax over keys n = nt*16 + qd*4 + i (cross-quad reduce)
            float mx = NEG_INF;
            #pragma unroll
            for (int nt = 0; nt < 4; ++nt) {
                if (nt < mtc) {
                    #pragma unroll
                    for (int i = 0; i < 4; ++i) {
                        bool kv = (nt * 16 + qd * 4 + i) < nb;
                        float val = kv ? S[nt][i] * scale : NEG_INF;
                        S[nt][i] = val;
                        mx = fmaxf(mx, val);
                    }
                } else {
                    S[nt] = (f32x4){NEG_INF, NEG_INF, NEG_INF, NEG_INF};
                }
            }
            mx = fmaxf(mx, __shfl_xor(mx, 16));
            mx = fmaxf(mx, __shfl_xor(mx, 32));
            float l = 0.f;
            #pragma unroll
            for (int nt = 0; nt < 4; ++nt)
                #pragma unroll
                for (int i = 0; i < 4; ++i) {
                    float e = __expf(S[nt][i] - mx);
                    S[nt][i] = e; l += e;
                }
            l += __shfl_xor(l, 16);
            l += __shfl_xor(l, 32);
            const float rl = 1.0f / l;
            #pragma unroll
            for (int nt = 0; nt < 4; ++nt)
                #pragma unroll
                for (int i = 0; i < 4; ++i)
                    S[nt][i] *= rl;                       // invalid keys -> exact 0

            // PV: O^T = V^T * P^T ; P^T frag via quad-shuffle from S^T C-tiles
            f32x4 o0 = {0.f,0.f,0.f,0.f}, o1 = {0.f,0.f,0.f,0.f};
            #pragma unroll
            for (int hk = 0; hk < 2; ++hk)
                if (hk * 2 < mtc) {
                    float pv[8];
                    #pragma unroll
                    for (int jj = 0; jj < 8; ++jj) {
                        int sl = r + q1 * 32 + (jj >> 2) * 16;
                        float f0 = __shfl(S[2*hk  ][jj & 3], sl);
                        float f1 = __shfl(S[2*hk+1][jj & 3], sl);
                        pv[jj] = (qd < 2) ? f0 : f1;
                    }
                    bf16x8 pf = {(bf16)pv[0],(bf16)pv[1],(bf16)pv[2],(bf16)pv[3],
                                 (bf16)pv[4],(bf16)pv[5],(bf16)pv[6],(bf16)pv[7]};
                    o0 = __builtin_amdgcn_mfma_f32_16x16x32_bf16(vf[0][hk], pf, o0, 0, 0, 0);
                    o1 = __builtin_amdgcn_mfma_f32_16x16x32_bf16(vf[1][hk], pf, o1, 0, 0, 0);
                }

            // ctx^T B-frag via quad-shuffle -> one b128 LDS write (overlays Q)
            float cv[8];
            #pragma unroll
            for (int jj = 0; jj < 8; ++jj) {
                int sl = r + q1 * 32 + (jj >> 2) * 16;
                float f0 = __shfl(o0[jj & 3], sl);
                float f1 = __shfl(o1[jj & 3], sl);
                cv[jj] = (qd < 2) ? f0 : f1;
            }
            bf16x8 cf = {(bf16)cv[0],(bf16)cv[1],(bf16)cv[2],(bf16)cv[3],
                         (bf16)cv[4],(bf16)cv[5],(bf16)cv[6],(bf16)cv[7]};
            *(bf16x8*)(Qld + mt * 512 + lane * 8) = cf;   // ctxS[h][mt][lane]
        }
    __syncthreads();

    // ---- stage 3: out^T = W_out * ctx^T ; float4 stores ----
    #pragma unroll
    for (int mt = 0; mt < 4; ++mt)
        if (mt < mtc) {
            bf16x8 cb[4];
            #pragma unroll
            for (int s = 0; s < 4; ++s)
                cb[s] = *(const bf16x8*)(s_lds + s * 6144 + mt * 512 + lane * 8);
            const int rowa = mt * 16 + r;
            #pragma unroll
            for (int t2 = 0; t2 < 2; ++t2) {
                f32x4 acc = {0.f,0.f,0.f,0.f};
                #pragma unroll
                for (int s = 0; s < 4; ++s)
                    acc = __builtin_amdgcn_mfma_f32_16x16x32_bf16(wof[t2][s], cb[s], acc, 0, 0, 0);
                if (rowa < nb) {
                    float4 o4 = make_float4(acc[0] + bo4[t2].x, acc[1] + bo4[t2].y,
                                            acc[2] + bo4[t2].z, acc[3] + bo4[t2].w);
                    *(float4*)(out + ((size_t)b * 64 + rowa) * 128
                               + (w * 2 + t2) * 16 + qd * 4) = o4;
                }
            }
        }
}

extern "C" void kernel_launch(void* const* d_in, const int* in_sizes, int n_in,
                              void* d_out, int out_size, void* d_ws, size_t ws_size,
                              hipStream_t stream)
{
    const float* att_in = (const float*)d_in[0];
    const float* w_in   = (const float*)d_in[1];
    const float* b_in   = (const float*)d_in[2];
    const float* w_out  = (const float*)d_in[3];
    const float* b_out  = (const float*)d_in[4];
    const int*   agents = (const int*)d_in[5];

    bf16* w_in_b  = (bf16*)d_ws;                         // 49152 * 2B
    bf16* w_out_b = w_in_b + 49152;                      // 16384 * 2B
    int*  offs    = (int*)((char*)d_ws + 98304 + 32768); // 2048 * 4B

    prep_kernel<<<65, 256, 0, stream>>>(w_in, w_out, agents, w_in_b, w_out_b, offs);
    attn_kernel<<<N_SCENES, 256, 0, stream>>>(att_in, b_in, b_out, w_in_b, w_out_b,
                                              agents, offs, (float*)d_out);
}